// Round 3
// baseline (914.608 us; speedup 1.0000x reference)
//
#include <hip/hip_runtime.h>

#define NN 50000
#define NE 800000

typedef unsigned short u16;
typedef __bf16 bf16x8 __attribute__((ext_vector_type(8)));
typedef float f32x4 __attribute__((ext_vector_type(4)));

__device__ __forceinline__ u16 f2b(float f){
  unsigned x = __float_as_uint(f);
  return (u16)((x + 0x7FFFu + ((x>>16)&1u)) >> 16);
}
#define MFMA16(a,b,c) __builtin_amdgcn_mfma_f32_16x16x32_bf16((a),(b),(c),0,0,0)

// ---------------- K0: fp32 weights -> bf16 [n][k] layout --------------------
__global__ void k_prep(const float* __restrict__ w1, const float* __restrict__ w2,
                       const float* __restrict__ w3, const float* __restrict__ wsep,
                       const float* __restrict__ wsrc, const float* __restrict__ wdst,
                       const float* __restrict__ wproj,
                       u16* __restrict__ w1T, u16* __restrict__ w2T,
                       u16* __restrict__ w3T, u16* __restrict__ wsepT,
                       u16* __restrict__ wsrcT, u16* __restrict__ wdstT,
                       u16* __restrict__ wprojT)
{
  int id = blockIdx.x*256 + threadIdx.x;
  if (id < 2048)  { int n=id>>5,  k=id&31;  w1T[id]   = f2b(w1[k*64+n]);    return; } id -= 2048;
  if (id < 4096)  { int n=id>>6,  k=id&63;  w2T[id]   = f2b(w2[k*64+n]);    return; } id -= 4096;
  if (id < 8192)  { int n=id>>6,  k=id&63;  w3T[id]   = f2b(w3[k*128+n]);   return; } id -= 8192;
  if (id < 32768) { int n=id>>7,  k=id&127; wsepT[id] = f2b(wsep[k*256+n]); return; } id -= 32768;
  if (id < 16384) { int n=id>>7,  k=id&127; wsrcT[id] = f2b(wsrc[k*128+n]); return; } id -= 16384;
  if (id < 16384) { int n=id>>7,  k=id&127; wdstT[id] = f2b(wdst[k*128+n]); return; } id -= 16384;
  if (id < 16384) { int n=id>>7,  k=id&127; wprojT[id]= f2b(wproj[k*128+n]); return; }
}

// ---------------- K1: node GEMM: msg_src = x@w_src+b, msg_dst = x@w_dst -----
__launch_bounds__(256)
__global__ void k_node(const float* __restrict__ x, const u16* __restrict__ wsrcT,
                       const u16* __restrict__ wdstT, const float* __restrict__ bsrc,
                       float* __restrict__ msgsrc, float* __restrict__ msgdst)
{
  __shared__ u16 sX[64*136];
  __shared__ u16 sW[128*136];
  __shared__ float sB[128];
  const int tid = threadIdx.x;
  const int n0 = blockIdx.x*64;
  for (int idx = tid; idx < 64*32; idx += 256){
    int r = idx>>5, s = idx&31;
    float4 v = make_float4(0.f,0.f,0.f,0.f);
    if (n0 + r < NN) v = *(const float4*)(x + (size_t)(n0+r)*128 + s*4);
    ushort4 o; o.x=f2b(v.x); o.y=f2b(v.y); o.z=f2b(v.z); o.w=f2b(v.w);
    *(ushort4*)(&sX[r*136 + s*4]) = o;
  }
  const int wave = tid>>6, lane = tid&63, l15 = lane&15, q = lane>>4;
  for (int half = 0; half < 2; ++half){
    const u16* wT = half ? wdstT : wsrcT;
    for (int idx = tid; idx < 128*16; idx += 256){
      int r = idx>>4, s = idx&15;
      *(uint4*)(&sW[r*136 + s*8]) = *(const uint4*)(wT + r*128 + s*8);
    }
    if (tid < 128) sB[tid] = half ? 0.0f : bsrc[tid];
    __syncthreads();
    f32x4 acc[8];
    #pragma unroll
    for (int n=0;n<8;++n) acc[n] = (f32x4){0.f,0.f,0.f,0.f};
    #pragma unroll
    for (int k0=0;k0<128;k0+=32){
      bf16x8 a = *(const bf16x8*)(&sX[(wave*16+l15)*136 + k0 + q*8]);
      #pragma unroll
      for (int n=0;n<8;++n){
        bf16x8 b = *(const bf16x8*)(&sW[(n*16+l15)*136 + k0 + q*8]);
        acc[n] = MFMA16(a,b,acc[n]);
      }
    }
    float* outp = half ? msgdst : msgsrc;
    #pragma unroll
    for (int n=0;n<8;++n){
      #pragma unroll
      for (int r=0;r<4;++r){
        int row = n0 + wave*16 + q*4 + r;
        if (row < NN) outp[(size_t)row*128 + n*16 + l15] = acc[n][r] + sB[n*16+l15];
      }
    }
    __syncthreads();
  }
}

// ---------------- K2: fused edge kernel (MLP + gather + w_sep + attention) --
#define PM 136
#define PH 72
#define PX 40
__launch_bounds__(256)
__global__ void k_edge(const float* __restrict__ escal, const float* __restrict__ eattr,
                       const int* __restrict__ esrc, const int* __restrict__ edst,
                       const float* __restrict__ msgsrc, const float* __restrict__ msgdst,
                       const u16* __restrict__ w1T, const u16* __restrict__ w2T,
                       const u16* __restrict__ w3T, const u16* __restrict__ wsepT,
                       const float* __restrict__ b1, const float* __restrict__ b2,
                       const float* __restrict__ b3, const float* __restrict__ bsep,
                       const float* __restrict__ adot,
                       float* __restrict__ num, float* __restrict__ denom)
{
  __shared__ __attribute__((aligned(16))) char pool[49408];
  u16*   sXs  = (u16*)(pool + 0);       // 64 x PX     (dead after L1)
  u16*   sW1  = (u16*)(pool + 5120);    // 64 x PX     (dead after L1)
  u16*   sW2  = (u16*)(pool + 10240);   // 64 x PH     (dead after L2)
  u16*   sH1  = (u16*)(pool + 19456);   // 64 x PH     (dead after L2)
  u16*   sMsg = (u16*)(pool + 28672);   // 64 x PM
  float* sB1  = (float*)(pool + 46080);
  float* sB2  = (float*)(pool + 46336);
  float* sB3  = (float*)(pool + 46592);
  float* sBs  = (float*)(pool + 47104);
  float* sAD  = (float*)(pool + 48128);
  float* sEA  = (float*)(pool + 48640);
  int*   sSrc = (int*)(pool + 48896);
  int*   sDst = (int*)(pool + 49152);
  u16*   sH2  = (u16*)(pool + 0);       // aliases sXs+sW1 (9216 <= 10240)
  u16*   sW3C = (u16*)(pool + 10240);   // aliases sW2
  u16*   sWsp = (u16*)(pool + 10240);   // aliases sW2+sH1 (17408 <= 18432)

  const int tid = threadIdx.x;
  const int e0 = blockIdx.x*64;
  const int wave = tid>>6, lane = tid&63, l15 = lane&15, q = lane>>4;

  // ---- phase A: stage inputs (fp32->bf16), weights, biases, meta
  {
    for (int j = tid; j < 512; j += 256){ int r=j>>3, s=j&7;
      float4 v = *(const float4*)(escal + (size_t)(e0+r)*32 + s*4);
      ushort4 o; o.x=f2b(v.x); o.y=f2b(v.y); o.z=f2b(v.z); o.w=f2b(v.w);
      *(ushort4*)&sXs[r*PX + s*4] = o; }
    if (tid < 256){ int r=tid>>2, s=tid&3;
      *(uint4*)&sW1[r*PX + s*8] = *(const uint4*)(w1T + r*32 + s*8); }
    for (int j = tid; j < 512; j += 256){ int r=j>>3, s=j&7;
      *(uint4*)&sW2[r*PH + s*8] = *(const uint4*)(w2T + r*64 + s*8); }
    if (tid < 64)  sB1[tid] = b1[tid];
    if (tid < 64)  sB2[tid] = b2[tid];
    if (tid < 128) sB3[tid] = b3[tid];
    sBs[tid] = bsep[tid];
    if (tid < 128) sAD[tid] = adot[tid];
    if (tid < 64){ sEA[tid] = eattr[e0+tid]; sSrc[tid] = esrc[e0+tid]; sDst[tid] = edst[e0+tid]; }
  }
  __syncthreads();

  // ---- phase B: MLP layer1 (K=32) + silu -> sH1
  {
    f32x4 acc[4];
    #pragma unroll
    for (int n=0;n<4;++n) acc[n] = (f32x4){0.f,0.f,0.f,0.f};
    bf16x8 a = *(const bf16x8*)&sXs[(wave*16+l15)*PX + q*8];
    #pragma unroll
    for (int n=0;n<4;++n){
      bf16x8 b = *(const bf16x8*)&sW1[(n*16+l15)*PX + q*8];
      acc[n] = MFMA16(a,b,acc[n]);
    }
    #pragma unroll
    for (int n=0;n<4;++n){
      #pragma unroll
      for (int r=0;r<4;++r){
        float v = acc[n][r] + sB1[n*16+l15];
        float h = v / (1.0f + __expf(-v));
        sH1[(wave*16+q*4+r)*PH + n*16+l15] = f2b(h);
      }
    }
  }
  __syncthreads();

  // ---- phase C: MLP layer2 (K=64) + silu -> sH2 (over sXs/sW1)
  {
    f32x4 acc[4];
    #pragma unroll
    for (int n=0;n<4;++n) acc[n] = (f32x4){0.f,0.f,0.f,0.f};
    #pragma unroll
    for (int k0=0;k0<64;k0+=32){
      bf16x8 a = *(const bf16x8*)&sH1[(wave*16+l15)*PH + k0 + q*8];
      #pragma unroll
      for (int n=0;n<4;++n){
        bf16x8 b = *(const bf16x8*)&sW2[(n*16+l15)*PH + k0 + q*8];
        acc[n] = MFMA16(a,b,acc[n]);
      }
    }
    #pragma unroll
    for (int n=0;n<4;++n){
      #pragma unroll
      for (int r=0;r<4;++r){
        float v = acc[n][r] + sB2[n*16+l15];
        float h = v / (1.0f + __expf(-v));
        sH2[(wave*16+q*4+r)*PH + n*16+l15] = f2b(h);
      }
    }
  }
  __syncthreads();

  // ---- phase D: MLP layer3 (K=64, 2 chunks of 64 cols) -> rad_w into sMsg
  for (int ch=0; ch<2; ++ch){
    for (int j = tid; j < 512; j += 256){ int r=j>>3, s=j&7;
      *(uint4*)&sW3C[r*PH + s*8] = *(const uint4*)(w3T + (size_t)(ch*64+r)*64 + s*8); }
    __syncthreads();
    const int m0 = (wave&1)*2, n0 = (wave>>1)*2;
    f32x4 acc[2][2];
    #pragma unroll
    for (int mm=0;mm<2;++mm)
      #pragma unroll
      for (int nn=0;nn<2;++nn) acc[mm][nn] = (f32x4){0.f,0.f,0.f,0.f};
    #pragma unroll
    for (int k0=0;k0<64;k0+=32){
      bf16x8 a0 = *(const bf16x8*)&sH2[((m0  )*16+l15)*PH + k0 + q*8];
      bf16x8 a1 = *(const bf16x8*)&sH2[((m0+1)*16+l15)*PH + k0 + q*8];
      bf16x8 b0 = *(const bf16x8*)&sW3C[((n0  )*16+l15)*PH + k0 + q*8];
      bf16x8 b1 = *(const bf16x8*)&sW3C[((n0+1)*16+l15)*PH + k0 + q*8];
      acc[0][0] = MFMA16(a0,b0,acc[0][0]);
      acc[1][0] = MFMA16(a1,b0,acc[1][0]);
      acc[0][1] = MFMA16(a0,b1,acc[0][1]);
      acc[1][1] = MFMA16(a1,b1,acc[1][1]);
    }
    #pragma unroll
    for (int mm=0;mm<2;++mm){
      #pragma unroll
      for (int nn=0;nn<2;++nn){
        int c = ch*64 + (n0+nn)*16 + l15;
        #pragma unroll
        for (int r=0;r<4;++r){
          float v = acc[mm][nn][r] + sB3[c];
          sMsg[((m0+mm)*16+q*4+r)*PM + c] = f2b(v);
        }
      }
    }
    __syncthreads();
  }

  // ---- phase E: gather node messages, message = (src+dst)*ea*radw (in-place)
  for (int idx = tid; idx < 64*32; idx += 256){
    int r = idx>>5, s = idx&31;
    int cs = s*4;
    float4 a4 = *(const float4*)(msgsrc + (size_t)sSrc[r]*128 + cs);
    float4 d4 = *(const float4*)(msgdst + (size_t)sDst[r]*128 + cs);
    float ea = sEA[r];
    ushort4 rw = *(ushort4*)&sMsg[r*PM + cs];
    ushort4 o;
    o.x = f2b((a4.x + d4.x) * ea * __uint_as_float(((unsigned)rw.x)<<16));
    o.y = f2b((a4.y + d4.y) * ea * __uint_as_float(((unsigned)rw.y)<<16));
    o.z = f2b((a4.z + d4.z) * ea * __uint_as_float(((unsigned)rw.z)<<16));
    o.w = f2b((a4.w + d4.w) * ea * __uint_as_float(((unsigned)rw.w)<<16));
    *(ushort4*)&sMsg[r*PM + cs] = o;
  }
  __syncthreads();

  // ---- phase F: message @ w_sep + fused softmax numerator/denominator.
  // No max-subtraction: |score| <~ 5 analytically, exp() safe in fp32, and
  // exp(m) cancels between numerator and denominator as in the reference.
  const int fm0 = (wave&1)*2, fn0 = (wave>>1)*2;
  for (int ch=0; ch<4; ++ch){
    for (int j = tid; j < 1024; j += 256){ int r=j>>4, s=j&15;
      *(uint4*)&sWsp[r*PM + s*8] = *(const uint4*)(wsepT + (size_t)(ch*64+r)*128 + s*8); }
    __syncthreads();
    f32x4 acc[2][2];   // [mm][0]=alpha subtile, [mm][1]=value subtile (same head)
    #pragma unroll
    for (int mm=0;mm<2;++mm)
      #pragma unroll
      for (int nn=0;nn<2;++nn) acc[mm][nn] = (f32x4){0.f,0.f,0.f,0.f};
    #pragma unroll
    for (int k0=0;k0<128;k0+=32){
      bf16x8 a0 = *(const bf16x8*)&sMsg[((fm0  )*16+l15)*PM + k0 + q*8];
      bf16x8 a1 = *(const bf16x8*)&sMsg[((fm0+1)*16+l15)*PM + k0 + q*8];
      bf16x8 b0 = *(const bf16x8*)&sWsp[((fn0  )*16+l15)*PM + k0 + q*8];
      bf16x8 b1 = *(const bf16x8*)&sWsp[((fn0+1)*16+l15)*PM + k0 + q*8];
      acc[0][0] = MFMA16(a0,b0,acc[0][0]);
      acc[1][0] = MFMA16(a1,b0,acc[1][0]);
      acc[0][1] = MFMA16(a0,b1,acc[0][1]);
      acc[1][1] = MFMA16(a1,b1,acc[1][1]);
    }
    {
      const int h  = ch*2 + (fn0>>1);        // head handled by this wave
      const int ca = ch*64 + fn0*16;         // alpha column base
      const float ba = sBs[ca + l15];
      const float bv = sBs[ca + 16 + l15];
      const float ad = sAD[h*16 + l15];
      #pragma unroll
      for (int mm=0;mm<2;++mm){
        #pragma unroll
        for (int r=0;r<4;++r){
          int eloc = (fm0+mm)*16 + q*4 + r;
          float av  = acc[mm][0][r] + ba;
          float sig = 1.0f/(1.0f + __expf(-av));
          float sl  = av*(0.2f + 0.8f*sig);       // smooth_leaky_relu(a=0.2)
          float contrib = sl * ad;
          contrib += __shfl_xor(contrib, 1);
          contrib += __shfl_xor(contrib, 2);
          contrib += __shfl_xor(contrib, 4);
          contrib += __shfl_xor(contrib, 8);      // all 16 lanes hold score
          float w  = __expf(contrib);
          int dst  = sDst[eloc];
          float vv = acc[mm][1][r] + bv;
          unsafeAtomicAdd(&num[(size_t)dst*128 + h*16 + l15], w*vv);
          if (l15 == 0) unsafeAtomicAdd(&denom[(size_t)dst*8 + h], w);
        }
      }
    }
    __syncthreads();
  }
}

// ---------------- K3: normalize + output projection -------------------------
__launch_bounds__(256)
__global__ void k_out(const float* __restrict__ num, const float* __restrict__ denom,
                      const u16* __restrict__ wprojT, const float* __restrict__ bproj,
                      float* __restrict__ out)
{
  __shared__ u16 sX[64*136];
  __shared__ u16 sW[128*136];
  __shared__ float sB[128];
  const int tid = threadIdx.x;
  const int n0 = blockIdx.x*64;
  for (int idx = tid; idx < 64*128; idx += 256){
    int r = idx>>7, c = idx&127;
    float xv = 0.f;
    int row = n0 + r;
    if (row < NN){
      float d = denom[row*8 + (c>>4)];
      xv = num[(size_t)row*128 + c] / (d + 1e-16f);
    }
    sX[r*136 + c] = f2b(xv);
  }
  for (int idx = tid; idx < 128*16; idx += 256){ int r=idx>>4, s=idx&15;
    *(uint4*)&sW[r*136 + s*8] = *(const uint4*)(wprojT + r*128 + s*8); }
  if (tid < 128) sB[tid] = bproj[tid];
  __syncthreads();
  const int wave = tid>>6, lane = tid&63, l15 = lane&15, q = lane>>4;
  f32x4 acc[8];
  #pragma unroll
  for (int n=0;n<8;++n) acc[n] = (f32x4){0.f,0.f,0.f,0.f};
  #pragma unroll
  for (int k0=0;k0<128;k0+=32){
    bf16x8 a = *(const bf16x8*)&sX[(wave*16+l15)*136 + k0 + q*8];
    #pragma unroll
    for (int n=0;n<8;++n){
      bf16x8 b = *(const bf16x8*)&sW[(n*16+l15)*136 + k0 + q*8];
      acc[n] = MFMA16(a,b,acc[n]);
    }
  }
  #pragma unroll
  for (int n=0;n<8;++n){
    #pragma unroll
    for (int r=0;r<4;++r){
      int row = n0 + wave*16 + q*4 + r;
      if (row < NN) out[(size_t)row*128 + n*16 + l15] = acc[n][r] + sB[n*16+l15];
    }
  }
}

// ---------------- host ------------------------------------------------------
extern "C" void kernel_launch(void* const* d_in, const int* in_sizes, int n_in,
                              void* d_out, int out_size, void* d_ws, size_t ws_size,
                              hipStream_t stream)
{
  const float* node_input = (const float*)d_in[0];
  const float* eattr = (const float*)d_in[2];
  const float* escal = (const float*)d_in[3];
  const int*   esrc  = (const int*)d_in[4];
  const int*   edst  = (const int*)d_in[5];
  const float* wsrc  = (const float*)d_in[7];
  const float* bsrc  = (const float*)d_in[8];
  const float* wdst  = (const float*)d_in[9];
  const float* w1    = (const float*)d_in[10];
  const float* b1    = (const float*)d_in[11];
  const float* w2    = (const float*)d_in[12];
  const float* b2    = (const float*)d_in[13];
  const float* w3    = (const float*)d_in[14];
  const float* b3    = (const float*)d_in[15];
  const float* wsep  = (const float*)d_in[16];
  const float* bsep  = (const float*)d_in[17];
  const float* adot  = (const float*)d_in[18];
  const float* wproj = (const float*)d_in[19];
  const float* bproj = (const float*)d_in[20];

  char* ws = (char*)d_ws;
  size_t off = 0;
  auto alloc = [&](size_t bytes)->void*{ void* p = ws + off; off += (bytes + 255) & ~(size_t)255; return p; };
  float* msgsrc = (float*)alloc((size_t)NN*128*4);   // 25.6 MB
  float* msgdst = (float*)alloc((size_t)NN*128*4);   // 25.6 MB
  float* num    = (float*)alloc((size_t)NN*128*4);   // 25.6 MB
  float* denom  = (float*)alloc((size_t)NN*8*4);     //  1.6 MB
  u16* w1T    = (u16*)alloc(2048*2);
  u16* w2T    = (u16*)alloc(4096*2);
  u16* w3T    = (u16*)alloc(8192*2);
  u16* wsepT  = (u16*)alloc(32768*2);
  u16* wsrcT  = (u16*)alloc(16384*2);
  u16* wdstT  = (u16*)alloc(16384*2);
  u16* wprojT = (u16*)alloc(16384*2);
  // total ~78.8 MB

  hipMemsetAsync(num,   0, (size_t)NN*128*4, stream);
  hipMemsetAsync(denom, 0, (size_t)NN*8*4,   stream);

  k_prep<<<376, 256, 0, stream>>>(w1,w2,w3,wsep,wsrc,wdst,wproj,
                                  w1T,w2T,w3T,wsepT,wsrcT,wdstT,wprojT);
  k_node<<<782, 256, 0, stream>>>(node_input, wsrcT, wdstT, bsrc, msgsrc, msgdst);
  k_edge<<<12500, 256, 0, stream>>>(escal, eattr, esrc, edst, msgsrc, msgdst,
                                    w1T, w2T, w3T, wsepT, b1, b2, b3, bsep, adot,
                                    num, denom);
  k_out<<<782, 256, 0, stream>>>(num, denom, wprojT, bproj, (float*)d_out);
}